// Round 8
// baseline (559.416 us; speedup 1.0000x reference)
//
#include <hip/hip_runtime.h>
#include <hip/hip_fp16.h>

#define M_TOTAL 512
#define N_TOTAL 11008
#define K_TOTAL 4096
#define BM 64
#define BN 64
#define BK 64
#define NT (K_TOTAL / BK)  // 64
#define LDK 72             // fallback kernel's padded stride

typedef short bf16x8 __attribute__((ext_vector_type(8)));
typedef _Float16 fp16x8 __attribute__((ext_vector_type(8)));
typedef float f32x4 __attribute__((ext_vector_type(4)));

// pack two fp32 into two bf16 (round-half-up) -> uint32 (f0 in low 16)
__device__ __forceinline__ unsigned int pack2_bf16(float f0, float f1) {
    unsigned int u0 = __builtin_bit_cast(unsigned int, f0) + 0x8000u;
    unsigned int u1 = __builtin_bit_cast(unsigned int, f1) + 0x8000u;
    return (u0 >> 16) | (u1 & 0xFFFF0000u);
}

// async global->LDS 16B DMA (LDS dest must be wave-uniform base + lane*16)
__device__ __forceinline__ void async_ld16(void* lds, const void* g) {
    __builtin_amdgcn_global_load_lds(
        (const __attribute__((address_space(1))) unsigned int*)g,
        (__attribute__((address_space(3))) unsigned int*)lds, 16, 0, 0);
}

// Per-wave inline dtype detection for weight_norm: 0=f32, 1=f16, 2=bf16.
__device__ __forceinline__ int detect_mode_wave(const void* __restrict__ wn) {
    const int lane = threadIdx.x & 63;
    const unsigned short* u16 = (const unsigned short*)wn;
    const float* f32p = (const float*)wn;
    const float vb = __builtin_bit_cast(float, (unsigned int)u16[lane] << 16);
    const float vh = __half2float(__builtin_bit_cast(__half, u16[lane]));
    const float vf = f32p[lane];
    const unsigned long long mb = __ballot(vb > 0.005f && vb < 0.12f);
    const unsigned long long mh = __ballot(vh > 0.005f && vh < 0.12f);
    (void)vf;
    return (mb == ~0ull) ? 2 : ((mh == ~0ull) ? 1 : 0);
}

// one-shot x fp32 -> fp16 (main kernel uses f16 MFMA)
__global__ void __launch_bounds__(256)
convert_x_kernel(const float* __restrict__ x, unsigned short* __restrict__ xb) {
    const int i = (blockIdx.x * 256 + threadIdx.x) * 4;
    const float4 v = *(const float4*)&x[i];
    const __half2 p0 = __floats2half2_rn(v.x, v.y);
    const __half2 p1 = __floats2half2_rn(v.z, v.w);
    *(uint2*)&xb[i] = make_uint2(__builtin_bit_cast(unsigned int, p0),
                                 __builtin_bit_cast(unsigned int, p1));
}

// -------- pipelined main kernel: 256 threads (4 waves), 64x64 tile.
// R7 = R3's schedule VERBATIM (inline B decode in the MFMA region, 1-step
// B prefetch, vmcnt(16)-counted raw barriers, A double-buffer) with the
// tile halved to 64x64: LDS 48->16 KB, acc 32->16 regs, so ~6 blocks/CU
// (~5.4 waves/SIMD from INDEPENDENT blocks) instead of 2.69. Attacks the
// measured latency-bound regime (all pipes <40% busy) with TLP, not
// schedule surgery.
__global__ void __launch_bounds__(256, 6)
l3b_gemm_pipe(const unsigned short* __restrict__ xb, const int* __restrict__ wq,
              const void* __restrict__ wnorm, const float* __restrict__ bias,
              float* __restrict__ out)
{
    // A only: XOR-swizzled, row stride 64 el (128 B); chunk p of row r holds
    // logical chunk p ^ (r & 7).
    __shared__ unsigned short As[2][BM * 64];  // 8 KB x2 = 16 KB

    const int tid  = threadIdx.x;
    const int mode = detect_mode_wave(wnorm);

    // XCD swizzle (bijective: 1376 = 8*172): within an XCD, consecutive w
    // walk m-tiles fastest -> ~21.5 n-tiles (~2.1 MB wq slice) per XCD L2.
    const int bid = blockIdx.x;                 // 0..1375
    const int w   = (bid & 7) * 172 + (bid >> 3);
    const int m0  = (w & 7) * BM;               // 8 m-tiles
    const int n0  = (w >> 3) * BN;              // 172 n-tiles

    const int wid  = tid >> 6;   // 0..3
    const int lane = tid & 63;
    const int quad = lane >> 4;
    const int lm   = lane & 15;
    const int wm   = (wid >> 1) * 32;   // 0,32 : wave tile 32x32
    const int wn_  = (wid & 1) * 32;    // 0,32

    // A-DMA: wave wid stages rows wid*8+(lane>>3) + j*32, j=0..1 (64 rows)
    // (all added row terms are 0 mod 8 -> swizzle index row&7 = (lane>>3)&7)
    const int arow0 = wid * 8 + (lane >> 3);
    const int acol  = ((lane & 7) ^ ((lane >> 3) & 7)) * 8;  // swizzle on global side
    const int aslot = (lane & 7) * 8;

    auto stageA = [&](int it, int buf) {
#pragma unroll
        for (int j = 0; j < 2; ++j) {          // 2 vmem insts per wave
            const int row = arow0 + j * 32;
            async_ld16(&As[buf][(row << 6) + aslot],
                       &xb[(size_t)(m0 + row) * K_TOTAL + it * 64 + acol]);
        }
    };

    auto loadNorm = [&](int g) -> float {
        if (mode == 0)      return ((const float*)wnorm)[g];
        else if (mode == 1) return __half2float(((const __half*)wnorm)[g]);
        else                return __builtin_bit_cast(float,
                               (unsigned int)((const unsigned short*)wnorm)[g] << 16);
    };

    // raw per-lane B prefetch (u = ks*2 + ni, consumption order): 16 vmem loads
    struct BP { int b0[4], b1[4], b2[4]; float nrm[4]; };

    auto loadBP = [&](int it, BP& P) {
#pragma unroll
        for (int u = 0; u < 4; ++u) {
            const int ks = u >> 1, ni = u & 1;
            const int c  = n0 + wn_ + ni * 16 + lm;       // my MFMA column
            const int g  = c * (K_TOTAL / 32) + it * 2 + ks;
            const int base = g * 12 + quad * 3;           // my k-chunk (quad*8)
            P.b0[u] = wq[base];
            P.b1[u] = wq[base + 1];
            P.b2[u] = wq[base + 2];
            P.nrm[u] = loadNorm(g);
        }
    };

    // fp16 mantissa-injection decode of 8 weights -> one B fragment
    auto decodeBF = [&](int b0, int b1, int b2, float nrm) -> fp16x8 {
        const __half2 A2 = __float2half2_rn(nrm * (16.0f / 7.0f));
        const __half2 B2 = __float2half2_rn(nrm * (-23.0f / 7.0f));
        const unsigned int bits =
            (unsigned)b0 | ((unsigned)b1 << 8) | ((unsigned)b2 << 16);
        union { unsigned int u[4]; fp16x8 v; } r;
#pragma unroll
        for (int j = 0; j < 4; ++j) {
            const unsigned int q0 = (bits >> (6 * j)) & 7u;
            const unsigned int q1 = (bits >> (6 * j + 3)) & 7u;
            const unsigned int y  = 0x3C003C00u | (q0 << 7) | (q1 << 23);
            r.u[j] = __builtin_bit_cast(unsigned int,
                       __hfma2(__builtin_bit_cast(__half2, y), A2, B2));
        }
        return r.v;
    };

    f32x4 acc[2][2];
#pragma unroll
    for (int i = 0; i < 2; ++i)
#pragma unroll
        for (int j = 0; j < 2; ++j) acc[i][j] = (f32x4){0.f, 0.f, 0.f, 0.f};

    // R3's MFMA region: inline decode (VALU overlaps ds_read/MFMA latency)
    auto mfmaStep = [&](const unsigned short* Asb, const BP& P) {
#pragma unroll
        for (int ks = 0; ks < 2; ++ks) {
            const int cswz = (((ks * 4 + quad) ^ (lm & 7)) << 3);
            fp16x8 aF[2];
#pragma unroll
            for (int mi = 0; mi < 2; ++mi)
                aF[mi] = *(const fp16x8*)&Asb[((wm + mi * 16 + lm) << 6) + cswz];
#pragma unroll
            for (int ni = 0; ni < 2; ++ni) {
                const int u = ks * 2 + ni;
                const fp16x8 bF = decodeBF(P.b0[u], P.b1[u], P.b2[u], P.nrm[u]);
                __builtin_amdgcn_s_setprio(1);
#pragma unroll
                for (int mi = 0; mi < 2; ++mi)
                    acc[mi][ni] = __builtin_amdgcn_mfma_f32_16x16x32_f16(
                        aF[mi], bF, acc[mi][ni], 0, 0, 0);
                __builtin_amdgcn_s_setprio(0);
            }
        }
    };

    // named double-buffer prefetch sets (no dynamic indexing -> no scratch)
    BP Pa, Pb;

    // prologue: full drain once
    stageA(0, 0);
    loadBP(0, Pa);
    __syncthreads();

    // R3 steady state verbatim. At each barrier: outstanding = 2 stageA DMA
    // (oldest) + 16 B-prefetch; vmcnt(16) completes the DMAs while B loads
    // stay in flight across the barrier (consumed next half-step).
    for (int it = 0; it < NT; it += 2) {
        stageA(it + 1, 1);
        __builtin_amdgcn_sched_barrier(0);
        loadBP(it + 1, Pb);
        __builtin_amdgcn_sched_barrier(0);
        mfmaStep(As[0], Pa);
        __builtin_amdgcn_sched_barrier(0);
        if (it + 2 < NT) {
            asm volatile("s_waitcnt vmcnt(16)" ::: "memory");
        } else {
            asm volatile("s_waitcnt vmcnt(0)" ::: "memory");
        }
        __builtin_amdgcn_s_barrier();
        __builtin_amdgcn_sched_barrier(0);

        if (it + 2 < NT) stageA(it + 2, 0);
        __builtin_amdgcn_sched_barrier(0);
        if (it + 2 < NT) loadBP(it + 2, Pa);
        __builtin_amdgcn_sched_barrier(0);
        mfmaStep(As[1], Pb);
        __builtin_amdgcn_sched_barrier(0);
        if (it + 2 < NT) {
            asm volatile("s_waitcnt vmcnt(16)" ::: "memory");
        } else {
            asm volatile("s_waitcnt vmcnt(0)" ::: "memory");
        }
        __builtin_amdgcn_s_barrier();
        __builtin_amdgcn_sched_barrier(0);
    }

    // epilogue: C/D layout col=lane&15, row=quad*4+reg
#pragma unroll
    for (int ni = 0; ni < 2; ++ni) {
        const int o  = n0 + wn_ + ni * 16 + lm;
        const float bv = bias[o];
#pragma unroll
        for (int mi = 0; mi < 2; ++mi) {
#pragma unroll
            for (int r = 0; r < 4; ++r) {
                const int m = m0 + wm + mi * 16 + quad * 4 + r;
                out[m * N_TOTAL + o] = acc[mi][ni][r] + bv;
            }
        }
    }
}

// ---------------- fallback (r2 kernel) if ws too small ----------------
__global__ void __launch_bounds__(256)
l3b_gemm_kernel(const float* __restrict__ x, const int* __restrict__ wq,
                const void* __restrict__ wnorm, const float* __restrict__ bias,
                float* __restrict__ out)
{
    __shared__ unsigned short As[128 * LDK];
    __shared__ unsigned short Bs[64 * LDK];

    const int mode = detect_mode_wave(wnorm);
    const int tid  = threadIdx.x;
    const int m0   = blockIdx.y * 128;
    const int n0   = blockIdx.x * 64;
    const int wid  = tid >> 6;
    const int lane = tid & 63;
    const int quad = lane >> 4;
    const int lm   = lane & 15;
    const int wm   = (wid >> 1) * 64;
    const int wn   = (wid & 1) * 32;

    f32x4 acc[4][2];
#pragma unroll
    for (int i = 0; i < 4; ++i)
#pragma unroll
        for (int j = 0; j < 2; ++j) acc[i][j] = (f32x4){0.f, 0.f, 0.f, 0.f};

    const int ar = tid >> 4;
    const int ac = (tid & 15) * 4;
    const int gin      = tid >> 1;
    const int half     = tid & 1;
    const int bn_local = gin >> 1;
    const int bkg      = gin & 1;

    for (int it = 0; it < NT; ++it) {
        const int k0 = it * BK;
        __syncthreads();
#pragma unroll
        for (int p = 0; p < 8; ++p) {
            const int row = p * 16 + ar;
            const float4 v = *(const float4*)&x[(m0 + row) * K_TOTAL + k0 + ac];
            *(uint2*)&As[row * LDK + ac] =
                make_uint2(pack2_bf16(v.x, v.y), pack2_bf16(v.z, v.w));
        }
        {
            const int g    = (n0 + bn_local) * (K_TOTAL / 32) + it * 2 + bkg;
            const int base = g * 12 + half * 6;
            const int2 w0 = *(const int2*)&wq[base];
            const int2 w1 = *(const int2*)&wq[base + 2];
            const int2 w2 = *(const int2*)&wq[base + 4];
            float nrm;
            if (mode == 0)      nrm = ((const float*)wnorm)[g];
            else if (mode == 1) nrm = __half2float(((const __half*)wnorm)[g]);
            else                nrm = __builtin_bit_cast(float,
                                    (unsigned int)((const unsigned short*)wnorm)[g] << 16);
            const float a = nrm * (2.0f / 7.0f);
            const float b = -nrm;
            const unsigned int bits0 =
                (unsigned)w0.x | ((unsigned)w0.y << 8) | ((unsigned)w1.x << 16);
            const unsigned int bits1 =
                (unsigned)w1.y | ((unsigned)w2.x << 8) | ((unsigned)w2.y << 16);
            unsigned int packs[8];
#pragma unroll
            for (int t3 = 0; t3 < 2; ++t3) {
                const unsigned int bits = t3 ? bits1 : bits0;
#pragma unroll
                for (int j = 0; j < 4; ++j) {
                    const float f0 = fmaf((float)((bits >> (6 * j)) & 7), a, b);
                    const float f1 = fmaf((float)((bits >> (6 * j + 3)) & 7), a, b);
                    packs[t3 * 4 + j] = pack2_bf16(f0, f1);
                }
            }
            unsigned int* dst = (unsigned int*)&Bs[bn_local * LDK + bkg * 32 + half * 16];
            *(uint4*)dst       = make_uint4(packs[0], packs[1], packs[2], packs[3]);
            *(uint4*)(dst + 4) = make_uint4(packs[4], packs[5], packs[6], packs[7]);
        }
        __syncthreads();
#pragma unroll
        for (int ks = 0; ks < 2; ++ks) {
            const int kb = ks * 32 + quad * 8;
            bf16x8 aF[4], bF[2];
#pragma unroll
            for (int mi = 0; mi < 4; ++mi)
                aF[mi] = *(const bf16x8*)&As[(wm + mi * 16 + lm) * LDK + kb];
#pragma unroll
            for (int ni = 0; ni < 2; ++ni)
                bF[ni] = *(const bf16x8*)&Bs[(wn + ni * 16 + lm) * LDK + kb];
#pragma unroll
            for (int mi = 0; mi < 4; ++mi)
#pragma unroll
                for (int ni = 0; ni < 2; ++ni)
                    acc[mi][ni] = __builtin_amdgcn_mfma_f32_16x16x32_bf16(
                        aF[mi], bF[ni], acc[mi][ni], 0, 0, 0);
        }
    }
#pragma unroll
    for (int ni = 0; ni < 2; ++ni) {
        const int o  = n0 + wn + ni * 16 + lm;
        const float bv = bias[o];
#pragma unroll
        for (int mi = 0; mi < 4; ++mi)
#pragma unroll
            for (int r = 0; r < 4; ++r) {
                const int m = m0 + wm + mi * 16 + quad * 4 + r;
                out[m * N_TOTAL + o] = acc[mi][ni][r] + bv;
            }
    }
}

extern "C" void kernel_launch(void* const* d_in, const int* in_sizes, int n_in,
                              void* d_out, int out_size, void* d_ws, size_t ws_size,
                              hipStream_t stream) {
    const float* x    = (const float*)d_in[0];
    const int*   wq   = (const int*)d_in[1];
    const void*  wn   = d_in[2];
    const float* bias = (const float*)d_in[3];
    float* out = (float*)d_out;

    const size_t need = 256 + (size_t)M_TOTAL * K_TOTAL * 2;
    if (ws_size >= need) {
        unsigned short* xb = (unsigned short*)((char*)d_ws + 256);
        convert_x_kernel<<<(M_TOTAL * K_TOTAL / 4) / 256, 256, 0, stream>>>(x, xb);
        l3b_gemm_pipe<<<(M_TOTAL / BM) * (N_TOTAL / BN), 256, 0, stream>>>(
            xb, wq, wn, bias, out);
    } else {
        dim3 grid(N_TOTAL / 64, M_TOTAL / 128);
        l3b_gemm_kernel<<<grid, 256, 0, stream>>>(x, wq, wn, bias, out);
    }
}

// Round 9
// 322.338 us; speedup vs baseline: 1.7355x; 1.7355x over previous
//
#include <hip/hip_runtime.h>
#include <hip/hip_fp16.h>

#define M_TOTAL 512
#define N_TOTAL 11008
#define K_TOTAL 4096
#define BM 128
#define BN 64
#define BK 64
#define NT (K_TOTAL / BK)  // 64
#define NT_HALF 32         // K-split x2: each block does 32 K-steps
#define LDK 72             // fallback kernel's padded stride

typedef short bf16x8 __attribute__((ext_vector_type(8)));
typedef _Float16 fp16x8 __attribute__((ext_vector_type(8)));
typedef float f32x4 __attribute__((ext_vector_type(4)));

// pack two fp32 into two bf16 (round-half-up) -> uint32 (f0 in low 16)
__device__ __forceinline__ unsigned int pack2_bf16(float f0, float f1) {
    unsigned int u0 = __builtin_bit_cast(unsigned int, f0) + 0x8000u;
    unsigned int u1 = __builtin_bit_cast(unsigned int, f1) + 0x8000u;
    return (u0 >> 16) | (u1 & 0xFFFF0000u);
}

// async global->LDS 16B DMA (LDS dest must be wave-uniform base + lane*16)
__device__ __forceinline__ void async_ld16(void* lds, const void* g) {
    __builtin_amdgcn_global_load_lds(
        (const __attribute__((address_space(1))) unsigned int*)g,
        (__attribute__((address_space(3))) unsigned int*)lds, 16, 0, 0);
}

// Per-wave inline dtype detection for weight_norm: 0=f32, 1=f16, 2=bf16.
__device__ __forceinline__ int detect_mode_wave(const void* __restrict__ wn) {
    const int lane = threadIdx.x & 63;
    const unsigned short* u16 = (const unsigned short*)wn;
    const float* f32p = (const float*)wn;
    const float vb = __builtin_bit_cast(float, (unsigned int)u16[lane] << 16);
    const float vh = __half2float(__builtin_bit_cast(__half, u16[lane]));
    const float vf = f32p[lane];
    const unsigned long long mb = __ballot(vb > 0.005f && vb < 0.12f);
    const unsigned long long mh = __ballot(vh > 0.005f && vh < 0.12f);
    (void)vf;
    return (mb == ~0ull) ? 2 : ((mh == ~0ull) ? 1 : 0);
}

// one-shot x fp32 -> fp16 (main kernel uses f16 MFMA)
__global__ void __launch_bounds__(256)
convert_x_kernel(const float* __restrict__ x, unsigned short* __restrict__ xb) {
    const int i = (blockIdx.x * 256 + threadIdx.x) * 4;
    const float4 v = *(const float4*)&x[i];
    const __half2 p0 = __floats2half2_rn(v.x, v.y);
    const __half2 p1 = __floats2half2_rn(v.z, v.w);
    *(uint2*)&xb[i] = make_uint2(__builtin_bit_cast(unsigned int, p0),
                                 __builtin_bit_cast(unsigned int, p1));
}

// -------- pipelined main kernel: 256 threads (4 waves), 128x64 tile.
// R8 = R3's schedule and per-wave shape VERBATIM (inline B decode in the
// MFMA region, 1-step B prefetch, vmcnt(16)-counted raw barriers, A
// double-buffer, LDS 32 KB, no launch-bounds tightening). Change: K-SPLIT
// x2 -> 1376 blocks (grid was the occupancy limit at 2.69 blocks/CU;
// LDS/VGPR allow 5). Each block does NT_HALF=32 K-steps; results combine
// via atomicAdd onto a zeroed out buffer (memset on-stream; race-free),
// khalf 0 contributes the bias.
__global__ void __launch_bounds__(256, 3)
l3b_gemm_pipe(const unsigned short* __restrict__ xb, const int* __restrict__ wq,
              const void* __restrict__ wnorm, const float* __restrict__ bias,
              float* __restrict__ out)
{
    // A only: XOR-swizzled, row stride 64 el (128 B); chunk p of row r holds
    // logical chunk p ^ (r & 7).
    __shared__ unsigned short As[2][BM * 64];  // 16 KB x2 = 32 KB

    const int tid  = threadIdx.x;
    const int mode = detect_mode_wave(wnorm);

    // XCD swizzle (bijective: 1376 = 8*172): within an XCD, consecutive w
    // walk khalf, then m-tiles, then n-tiles -> ~21.5 n-tiles (~2.2 MB wq
    // slice) per XCD L2, same footprint as R3.
    const int bid   = blockIdx.x;               // 0..1375
    const int w     = (bid & 7) * 172 + (bid >> 3);
    const int khalf = w & 1;
    const int tile  = w >> 1;                   // 0..687
    const int m0    = (tile & 3) * BM;
    const int n0    = (tile >> 2) * BN;
    const int it0   = khalf * NT_HALF;
    const int itEnd = it0 + NT_HALF;

    const int wid  = tid >> 6;   // 0..3
    const int lane = tid & 63;
    const int quad = lane >> 4;
    const int lm   = lane & 15;
    const int wm   = (wid >> 1) * 64;   // 0,64
    const int wn_  = (wid & 1) * 32;    // 0,32

    // A-DMA: wave wid stages rows wid*8+(lane>>3) + j*32, j=0..3
    const int arow0 = wid * 8 + (lane >> 3);
    const int acol  = ((lane & 7) ^ ((lane >> 3) & 7)) * 8;  // swizzle on global side
    const int aslot = (lane & 7) * 8;

    auto stageA = [&](int it, int buf) {
#pragma unroll
        for (int j = 0; j < 4; ++j) {
            const int row = arow0 + j * 32;
            async_ld16(&As[buf][(row << 6) + aslot],
                       &xb[(size_t)(m0 + row) * K_TOTAL + it * 64 + acol]);
        }
    };

    auto loadNorm = [&](int g) -> float {
        if (mode == 0)      return ((const float*)wnorm)[g];
        else if (mode == 1) return __half2float(((const __half*)wnorm)[g]);
        else                return __builtin_bit_cast(float,
                               (unsigned int)((const unsigned short*)wnorm)[g] << 16);
    };

    // raw per-lane B prefetch (u = ks*2 + ni, consumption order): 16 vmem loads
    struct BP { int b0[4], b1[4], b2[4]; float nrm[4]; };

    auto loadBP = [&](int it, BP& P) {
#pragma unroll
        for (int u = 0; u < 4; ++u) {
            const int ks = u >> 1, ni = u & 1;
            const int c  = n0 + wn_ + ni * 16 + lm;       // my MFMA column
            const int g  = c * (K_TOTAL / 32) + it * 2 + ks;
            const int base = g * 12 + quad * 3;           // my k-chunk (quad*8)
            P.b0[u] = wq[base];
            P.b1[u] = wq[base + 1];
            P.b2[u] = wq[base + 2];
            P.nrm[u] = loadNorm(g);
        }
    };

    // fp16 mantissa-injection decode of 8 weights -> one B fragment
    auto decodeBF = [&](int b0, int b1, int b2, float nrm) -> fp16x8 {
        const __half2 A2 = __float2half2_rn(nrm * (16.0f / 7.0f));
        const __half2 B2 = __float2half2_rn(nrm * (-23.0f / 7.0f));
        const unsigned int bits =
            (unsigned)b0 | ((unsigned)b1 << 8) | ((unsigned)b2 << 16);
        union { unsigned int u[4]; fp16x8 v; } r;
#pragma unroll
        for (int j = 0; j < 4; ++j) {
            const unsigned int q0 = (bits >> (6 * j)) & 7u;
            const unsigned int q1 = (bits >> (6 * j + 3)) & 7u;
            const unsigned int y  = 0x3C003C00u | (q0 << 7) | (q1 << 23);
            r.u[j] = __builtin_bit_cast(unsigned int,
                       __hfma2(__builtin_bit_cast(__half2, y), A2, B2));
        }
        return r.v;
    };

    f32x4 acc[4][2];
#pragma unroll
    for (int i = 0; i < 4; ++i)
#pragma unroll
        for (int j = 0; j < 2; ++j) acc[i][j] = (f32x4){0.f, 0.f, 0.f, 0.f};

    // R3's MFMA region: inline decode (VALU overlaps ds_read/MFMA latency)
    auto mfmaStep = [&](const unsigned short* Asb, const BP& P) {
#pragma unroll
        for (int ks = 0; ks < 2; ++ks) {
            const int cswz = (((ks * 4 + quad) ^ (lm & 7)) << 3);
            fp16x8 aF[4];
#pragma unroll
            for (int mi = 0; mi < 4; ++mi)
                aF[mi] = *(const fp16x8*)&Asb[((wm + mi * 16 + lm) << 6) + cswz];
#pragma unroll
            for (int ni = 0; ni < 2; ++ni) {
                const int u = ks * 2 + ni;
                const fp16x8 bF = decodeBF(P.b0[u], P.b1[u], P.b2[u], P.nrm[u]);
                __builtin_amdgcn_s_setprio(1);
#pragma unroll
                for (int mi = 0; mi < 4; ++mi)
                    acc[mi][ni] = __builtin_amdgcn_mfma_f32_16x16x32_f16(
                        aF[mi], bF, acc[mi][ni], 0, 0, 0);
                __builtin_amdgcn_s_setprio(0);
            }
        }
    };

    // named double-buffer prefetch sets (no dynamic indexing -> no scratch)
    BP Pa, Pb;

    // prologue: full drain once
    stageA(it0, 0);
    loadBP(it0, Pa);
    __syncthreads();

    // R3 steady state verbatim over [it0, itEnd). At each barrier:
    // outstanding = 4 stageA DMA (oldest) + 16 B-prefetch; vmcnt(16)
    // completes the DMAs while B loads stay in flight across the barrier.
    for (int it = it0; it < itEnd; it += 2) {
        stageA(it + 1, 1);
        __builtin_amdgcn_sched_barrier(0);
        loadBP(it + 1, Pb);
        __builtin_amdgcn_sched_barrier(0);
        mfmaStep(As[0], Pa);
        __builtin_amdgcn_sched_barrier(0);
        if (it + 2 < itEnd) {
            asm volatile("s_waitcnt vmcnt(16)" ::: "memory");
        } else {
            asm volatile("s_waitcnt vmcnt(0)" ::: "memory");
        }
        __builtin_amdgcn_s_barrier();
        __builtin_amdgcn_sched_barrier(0);

        if (it + 2 < itEnd) stageA(it + 2, 0);
        __builtin_amdgcn_sched_barrier(0);
        if (it + 2 < itEnd) loadBP(it + 2, Pa);
        __builtin_amdgcn_sched_barrier(0);
        mfmaStep(As[1], Pb);
        __builtin_amdgcn_sched_barrier(0);
        if (it + 2 < itEnd) {
            asm volatile("s_waitcnt vmcnt(16)" ::: "memory");
        } else {
            asm volatile("s_waitcnt vmcnt(0)" ::: "memory");
        }
        __builtin_amdgcn_s_barrier();
        __builtin_amdgcn_sched_barrier(0);
    }

    // epilogue: C/D layout col=lane&15, row=quad*4+reg.
    // K-split combine: atomicAdd onto zeroed out; khalf 0 adds the bias.
#pragma unroll
    for (int ni = 0; ni < 2; ++ni) {
        const int o  = n0 + wn_ + ni * 16 + lm;
        const float bv = (khalf == 0) ? bias[o] : 0.0f;
#pragma unroll
        for (int mi = 0; mi < 4; ++mi) {
#pragma unroll
            for (int r = 0; r < 4; ++r) {
                const int m = m0 + wm + mi * 16 + quad * 4 + r;
                atomicAdd(&out[m * N_TOTAL + o], acc[mi][ni][r] + bv);
            }
        }
    }
}

// ---------------- fallback (r2 kernel) if ws too small ----------------
__global__ void __launch_bounds__(256)
l3b_gemm_kernel(const float* __restrict__ x, const int* __restrict__ wq,
                const void* __restrict__ wnorm, const float* __restrict__ bias,
                float* __restrict__ out)
{
    __shared__ unsigned short As[128 * LDK];
    __shared__ unsigned short Bs[64 * LDK];

    const int mode = detect_mode_wave(wnorm);
    const int tid  = threadIdx.x;
    const int m0   = blockIdx.y * 128;
    const int n0   = blockIdx.x * 64;
    const int wid  = tid >> 6;
    const int lane = tid & 63;
    const int quad = lane >> 4;
    const int lm   = lane & 15;
    const int wm   = (wid >> 1) * 64;
    const int wn   = (wid & 1) * 32;

    f32x4 acc[4][2];
#pragma unroll
    for (int i = 0; i < 4; ++i)
#pragma unroll
        for (int j = 0; j < 2; ++j) acc[i][j] = (f32x4){0.f, 0.f, 0.f, 0.f};

    const int ar = tid >> 4;
    const int ac = (tid & 15) * 4;
    const int gin      = tid >> 1;
    const int half     = tid & 1;
    const int bn_local = gin >> 1;
    const int bkg      = gin & 1;

    for (int it = 0; it < NT; ++it) {
        const int k0 = it * BK;
        __syncthreads();
#pragma unroll
        for (int p = 0; p < 8; ++p) {
            const int row = p * 16 + ar;
            const float4 v = *(const float4*)&x[(m0 + row) * K_TOTAL + k0 + ac];
            *(uint2*)&As[row * LDK + ac] =
                make_uint2(pack2_bf16(v.x, v.y), pack2_bf16(v.z, v.w));
        }
        {
            const int g    = (n0 + bn_local) * (K_TOTAL / 32) + it * 2 + bkg;
            const int base = g * 12 + half * 6;
            const int2 w0 = *(const int2*)&wq[base];
            const int2 w1 = *(const int2*)&wq[base + 2];
            const int2 w2 = *(const int2*)&wq[base + 4];
            float nrm;
            if (mode == 0)      nrm = ((const float*)wnorm)[g];
            else if (mode == 1) nrm = __half2float(((const __half*)wnorm)[g]);
            else                nrm = __builtin_bit_cast(float,
                                    (unsigned int)((const unsigned short*)wnorm)[g] << 16);
            const float a = nrm * (2.0f / 7.0f);
            const float b = -nrm;
            const unsigned int bits0 =
                (unsigned)w0.x | ((unsigned)w0.y << 8) | ((unsigned)w1.x << 16);
            const unsigned int bits1 =
                (unsigned)w1.y | ((unsigned)w2.x << 8) | ((unsigned)w2.y << 16);
            unsigned int packs[8];
#pragma unroll
            for (int t3 = 0; t3 < 2; ++t3) {
                const unsigned int bits = t3 ? bits1 : bits0;
#pragma unroll
                for (int j = 0; j < 4; ++j) {
                    const float f0 = fmaf((float)((bits >> (6 * j)) & 7), a, b);
                    const float f1 = fmaf((float)((bits >> (6 * j + 3)) & 7), a, b);
                    packs[t3 * 4 + j] = pack2_bf16(f0, f1);
                }
            }
            unsigned int* dst = (unsigned int*)&Bs[bn_local * LDK + bkg * 32 + half * 16];
            *(uint4*)dst       = make_uint4(packs[0], packs[1], packs[2], packs[3]);
            *(uint4*)(dst + 4) = make_uint4(packs[4], packs[5], packs[6], packs[7]);
        }
        __syncthreads();
#pragma unroll
        for (int ks = 0; ks < 2; ++ks) {
            const int kb = ks * 32 + quad * 8;
            bf16x8 aF[4], bF[2];
#pragma unroll
            for (int mi = 0; mi < 4; ++mi)
                aF[mi] = *(const bf16x8*)&As[(wm + mi * 16 + lm) * LDK + kb];
#pragma unroll
            for (int ni = 0; ni < 2; ++ni)
                bF[ni] = *(const bf16x8*)&Bs[(wn + ni * 16 + lm) * LDK + kb];
#pragma unroll
            for (int mi = 0; mi < 4; ++mi)
#pragma unroll
                for (int ni = 0; ni < 2; ++ni)
                    acc[mi][ni] = __builtin_amdgcn_mfma_f32_16x16x32_bf16(
                        aF[mi], bF[ni], acc[mi][ni], 0, 0, 0);
        }
    }
#pragma unroll
    for (int ni = 0; ni < 2; ++ni) {
        const int o  = n0 + wn + ni * 16 + lm;
        const float bv = bias[o];
#pragma unroll
        for (int mi = 0; mi < 4; ++mi)
#pragma unroll
            for (int r = 0; r < 4; ++r) {
                const int m = m0 + wm + mi * 16 + quad * 4 + r;
                out[m * N_TOTAL + o] = acc[mi][ni][r] + bv;
            }
    }
}

extern "C" void kernel_launch(void* const* d_in, const int* in_sizes, int n_in,
                              void* d_out, int out_size, void* d_ws, size_t ws_size,
                              hipStream_t stream) {
    const float* x    = (const float*)d_in[0];
    const int*   wq   = (const int*)d_in[1];
    const void*  wn   = d_in[2];
    const float* bias = (const float*)d_in[3];
    float* out = (float*)d_out;

    const size_t need = 256 + (size_t)M_TOTAL * K_TOTAL * 2;
    if (ws_size >= need) {
        unsigned short* xb = (unsigned short*)((char*)d_ws + 256);
        // zero out for the K-split atomic combine (async, same stream)
        hipMemsetAsync(out, 0, (size_t)M_TOTAL * N_TOTAL * sizeof(float), stream);
        convert_x_kernel<<<(M_TOTAL * K_TOTAL / 4) / 256, 256, 0, stream>>>(x, xb);
        l3b_gemm_pipe<<<(M_TOTAL / BM) * (N_TOTAL / BN) * 2, 256, 0, stream>>>(
            xb, wq, wn, bias, out);
    } else {
        dim3 grid(N_TOTAL / 64, M_TOTAL / 128);
        l3b_gemm_kernel<<<grid, 256, 0, stream>>>(x, wq, wn, bias, out);
    }
}

// Round 12
// 195.114 us; speedup vs baseline: 2.8671x; 1.6520x over previous
//
#include <hip/hip_runtime.h>
#include <hip/hip_fp16.h>

#define M_TOTAL 512
#define N_TOTAL 11008
#define K_TOTAL 4096
#define BM 128
#define BN 64
#define BK 64
#define NT (K_TOTAL / BK)  // 64
#define NUM_GROUPS (N_TOTAL * K_TOTAL / 32)  // 1409024
#define LDK 72             // fallback kernel's padded stride

typedef short bf16x8 __attribute__((ext_vector_type(8)));
typedef _Float16 fp16x8 __attribute__((ext_vector_type(8)));
typedef float f32x4 __attribute__((ext_vector_type(4)));

// pack two fp32 into two bf16 (round-half-up) -> uint32 (f0 in low 16)
__device__ __forceinline__ unsigned int pack2_bf16(float f0, float f1) {
    unsigned int u0 = __builtin_bit_cast(unsigned int, f0) + 0x8000u;
    unsigned int u1 = __builtin_bit_cast(unsigned int, f1) + 0x8000u;
    return (u0 >> 16) | (u1 & 0xFFFF0000u);
}

// async global->LDS 16B DMA (LDS dest must be wave-uniform base + lane*16)
__device__ __forceinline__ void async_ld16(void* lds, const void* g) {
    __builtin_amdgcn_global_load_lds(
        (const __attribute__((address_space(1))) unsigned int*)g,
        (__attribute__((address_space(3))) unsigned int*)lds, 16, 0, 0);
}

// Per-wave inline dtype detection for weight_norm: 0=f32, 1=f16, 2=bf16.
__device__ __forceinline__ int detect_mode_wave(const void* __restrict__ wn) {
    const int lane = threadIdx.x & 63;
    const unsigned short* u16 = (const unsigned short*)wn;
    const float* f32p = (const float*)wn;
    const float vb = __builtin_bit_cast(float, (unsigned int)u16[lane] << 16);
    const float vh = __half2float(__builtin_bit_cast(__half, u16[lane]));
    const float vf = f32p[lane];
    const unsigned long long mb = __ballot(vb > 0.005f && vb < 0.12f);
    const unsigned long long mh = __ballot(vh > 0.005f && vh < 0.12f);
    (void)vf;
    return (mb == ~0ull) ? 2 : ((mh == ~0ull) ? 1 : 0);
}

__device__ __forceinline__ float load_norm_mode(const void* __restrict__ wn,
                                                int mode, int g) {
    if (mode == 0)      return ((const float*)wn)[g];
    else if (mode == 1) return __half2float(((const __half*)wn)[g]);
    else                return __builtin_bit_cast(float,
                           (unsigned int)((const unsigned short*)wn)[g] << 16);
}

// one-shot x fp32 -> fp16 (GEMM uses f16 MFMA)
__global__ void __launch_bounds__(256)
convert_x_kernel(const float* __restrict__ x, unsigned short* __restrict__ xb) {
    const int i = (blockIdx.x * 256 + threadIdx.x) * 4;
    const float4 v = *(const float4*)&x[i];
    const __half2 p0 = __floats2half2_rn(v.x, v.y);
    const __half2 p1 = __floats2half2_rn(v.z, v.w);
    *(uint2*)&xb[i] = make_uint2(__builtin_bit_cast(unsigned int, p0),
                                 __builtin_bit_cast(unsigned int, p1));
}

// one-shot W decode: 1 thread per 32-weight group -> fp16 [N][K] in ws.
// Reads 3 int4 (48 B, 16B-aligned: byte offset 48g) + 1 norm; decodes via
// fp16 mantissa-injection (identical math to the fused kernel); writes 64 B.
__global__ void __launch_bounds__(256)
decode_w_kernel(const int* __restrict__ wq, const void* __restrict__ wnorm,
                unsigned short* __restrict__ wf) {
    const int mode = detect_mode_wave(wnorm);
    const int g = blockIdx.x * 256 + threadIdx.x;       // 0..NUM_GROUPS-1
    const int4* wq4 = (const int4*)wq;
    const int4 w0 = wq4[g * 3];
    const int4 w1 = wq4[g * 3 + 1];
    const int4 w2 = wq4[g * 3 + 2];
    const float nrm = load_norm_mode(wnorm, mode, g);
    const __half2 A2 = __float2half2_rn(nrm * (16.0f / 7.0f));
    const __half2 B2 = __float2half2_rn(nrm * (-23.0f / 7.0f));
    const unsigned int bits_s[4] = {
        (unsigned)w0.x | ((unsigned)w0.y << 8) | ((unsigned)w0.z << 16),
        (unsigned)w0.w | ((unsigned)w1.x << 8) | ((unsigned)w1.y << 16),
        (unsigned)w1.z | ((unsigned)w1.w << 8) | ((unsigned)w2.x << 16),
        (unsigned)w2.y | ((unsigned)w2.z << 8) | ((unsigned)w2.w << 16)};
    unsigned int packs[16];
#pragma unroll
    for (int s = 0; s < 4; ++s) {
        const unsigned int bits = bits_s[s];
#pragma unroll
        for (int j = 0; j < 4; ++j) {
            const unsigned int q0 = (bits >> (6 * j)) & 7u;
            const unsigned int q1 = (bits >> (6 * j + 3)) & 7u;
            const unsigned int y  = 0x3C003C00u | (q0 << 7) | (q1 << 23);
            packs[s * 4 + j] = __builtin_bit_cast(unsigned int,
                __hfma2(__builtin_bit_cast(__half2, y), A2, B2));
        }
    }
    const int o  = g >> 7;                 // output row (column of GEMM B)
    const int kb = (g & 127) * 32;         // k offset
    uint4* dst = (uint4*)&wf[(size_t)o * K_TOTAL + kb];
    dst[0] = make_uint4(packs[0], packs[1], packs[2], packs[3]);
    dst[1] = make_uint4(packs[4], packs[5], packs[6], packs[7]);
    dst[2] = make_uint4(packs[8], packs[9], packs[10], packs[11]);
    dst[3] = make_uint4(packs[12], packs[13], packs[14], packs[15]);
}

// -------- clean m97-style GEMM: 256 threads (4 waves), 128x64 tile.
// Both A (fp16 x) and B (pre-decoded fp16 W) staged via global_load_lds,
// double-buffered, plain __syncthreads (compiler-managed waits; proven
// structure). XOR-swizzled LDS, 0 bank conflicts. No inline asm.
__global__ void __launch_bounds__(256, 3)
l3b_gemm_ws(const unsigned short* __restrict__ xb, const unsigned short* __restrict__ wf,
            const float* __restrict__ bias, float* __restrict__ out)
{
    // row stride 64 el (128 B); 16-B chunk p of row r holds chunk p ^ (r&7)
    __shared__ unsigned short As[2][BM * 64];  // 16 KB x2
    __shared__ unsigned short Bs[2][BN * 64];  // 8 KB x2 -> 48 KB (3 blk/CU)

    const int tid = threadIdx.x;

    // XCD swizzle (bijective: 688 = 8*86)
    const int bid = blockIdx.x;                 // 0..687
    const int w   = (bid & 7) * 86 + (bid >> 3);
    const int m0  = (w & 3) * BM;
    const int n0  = (w >> 2) * BN;

    const int wid  = tid >> 6;   // 0..3
    const int lane = tid & 63;
    const int quad = lane >> 4;
    const int lm   = lane & 15;
    const int wm   = (wid >> 1) * 64;   // 0,64
    const int wn_  = (wid & 1) * 32;    // 0,32

    // DMA lane mapping (shared by A and B staging)
    const int row0  = wid * 8 + (lane >> 3);
    const int gcol  = ((lane & 7) ^ ((lane >> 3) & 7)) * 8;  // pre-swizzled src
    const int slot  = (lane & 7) * 8;

    auto stageA = [&](int it, int buf) {
#pragma unroll
        for (int j = 0; j < 4; ++j) {            // 128 rows
            const int row = row0 + j * 32;
            async_ld16(&As[buf][(row << 6) + slot],
                       &xb[(size_t)(m0 + row) * K_TOTAL + it * 64 + gcol]);
        }
    };
    auto stageB = [&](int it, int buf) {
#pragma unroll
        for (int j = 0; j < 2; ++j) {            // 64 rows
            const int row = row0 + j * 32;
            async_ld16(&Bs[buf][(row << 6) + slot],
                       &wf[(size_t)(n0 + row) * K_TOTAL + it * 64 + gcol]);
        }
    };

    f32x4 acc[4][2];
#pragma unroll
    for (int i = 0; i < 4; ++i)
#pragma unroll
        for (int j = 0; j < 2; ++j) acc[i][j] = (f32x4){0.f, 0.f, 0.f, 0.f};

    auto mfmaTile = [&](const unsigned short* Asb, const unsigned short* Bsb) {
#pragma unroll
        for (int ks = 0; ks < 2; ++ks) {
            const int cswz = (((ks * 4 + quad) ^ (lm & 7)) << 3);
            fp16x8 aF[4], bF[2];
#pragma unroll
            for (int mi = 0; mi < 4; ++mi)
                aF[mi] = *(const fp16x8*)&Asb[((wm + mi * 16 + lm) << 6) + cswz];
#pragma unroll
            for (int ni = 0; ni < 2; ++ni)
                bF[ni] = *(const fp16x8*)&Bsb[((wn_ + ni * 16 + lm) << 6) + cswz];
            __builtin_amdgcn_s_setprio(1);
#pragma unroll
            for (int mi = 0; mi < 4; ++mi)
#pragma unroll
                for (int ni = 0; ni < 2; ++ni)
                    acc[mi][ni] = __builtin_amdgcn_mfma_f32_16x16x32_f16(
                        aF[mi], bF[ni], acc[mi][ni], 0, 0, 0);
            __builtin_amdgcn_s_setprio(0);
        }
    };

    // prologue
    stageA(0, 0);
    stageB(0, 0);
    __syncthreads();

    // m97 pattern: stage next buffer, compute current, one barrier per step.
    for (int it = 0; it < NT; ++it) {
        const int buf = it & 1;
        if (it + 1 < NT) { stageA(it + 1, buf ^ 1); stageB(it + 1, buf ^ 1); }
        mfmaTile(As[buf], Bs[buf]);
        __syncthreads();
    }

    // epilogue: C/D layout col=lane&15, row=quad*4+reg
#pragma unroll
    for (int ni = 0; ni < 2; ++ni) {
        const int o  = n0 + wn_ + ni * 16 + lm;
        const float bv = bias[o];
#pragma unroll
        for (int mi = 0; mi < 4; ++mi) {
#pragma unroll
            for (int r = 0; r < 4; ++r) {
                const int m = m0 + wm + mi * 16 + quad * 4 + r;
                out[m * N_TOTAL + o] = acc[mi][ni][r] + bv;
            }
        }
    }
}

// -------- mid fallback: R3 fused kernel VERBATIM (95.4 us, verified) --------
__global__ void __launch_bounds__(256, 3)
l3b_gemm_pipe(const unsigned short* __restrict__ xb, const int* __restrict__ wq,
              const void* __restrict__ wnorm, const float* __restrict__ bias,
              float* __restrict__ out)
{
    __shared__ unsigned short As[2][BM * 64];  // 16 KB x2 = 32 KB

    const int tid  = threadIdx.x;
    const int mode = detect_mode_wave(wnorm);

    const int bid = blockIdx.x;                 // 0..687
    const int w   = (bid & 7) * 86 + (bid >> 3);
    const int m0  = (w & 3) * BM;
    const int n0  = (w >> 2) * BN;

    const int wid  = tid >> 6;
    const int lane = tid & 63;
    const int quad = lane >> 4;
    const int lm   = lane & 15;
    const int wm   = (wid >> 1) * 64;
    const int wn_  = (wid & 1) * 32;

    const int arow0 = wid * 8 + (lane >> 3);
    const int acol  = ((lane & 7) ^ ((lane >> 3) & 7)) * 8;
    const int aslot = (lane & 7) * 8;

    auto stageA = [&](int it, int buf) {
#pragma unroll
        for (int j = 0; j < 4; ++j) {
            const int row = arow0 + j * 32;
            async_ld16(&As[buf][(row << 6) + aslot],
                       &xb[(size_t)(m0 + row) * K_TOTAL + it * 64 + acol]);
        }
    };

    struct BP { int b0[4], b1[4], b2[4]; float nrm[4]; };

    auto loadBP = [&](int it, BP& P) {
#pragma unroll
        for (int u = 0; u < 4; ++u) {
            const int ks = u >> 1, ni = u & 1;
            const int c  = n0 + wn_ + ni * 16 + lm;
            const int g  = c * (K_TOTAL / 32) + it * 2 + ks;
            const int base = g * 12 + quad * 3;
            P.b0[u] = ((const int*)wq)[base];
            P.b1[u] = ((const int*)wq)[base + 1];
            P.b2[u] = ((const int*)wq)[base + 2];
            P.nrm[u] = load_norm_mode(wnorm, mode, g);
        }
    };

    auto decodeBF = [&](int b0, int b1, int b2, float nrm) -> fp16x8 {
        const __half2 A2 = __float2half2_rn(nrm * (16.0f / 7.0f));
        const __half2 B2 = __float2half2_rn(nrm * (-23.0f / 7.0f));
        const unsigned int bits =
            (unsigned)b0 | ((unsigned)b1 << 8) | ((unsigned)b2 << 16);
        union { unsigned int u[4]; fp16x8 v; } r;
#pragma unroll
        for (int j = 0; j < 4; ++j) {
            const unsigned int q0 = (bits >> (6 * j)) & 7u;
            const unsigned int q1 = (bits >> (6 * j + 3)) & 7u;
            const unsigned int y  = 0x3C003C00u | (q0 << 7) | (q1 << 23);
            r.u[j] = __builtin_bit_cast(unsigned int,
                       __hfma2(__builtin_bit_cast(__half2, y), A2, B2));
        }
        return r.v;
    };

    f32x4 acc[4][2];
#pragma unroll
    for (int i = 0; i < 4; ++i)
#pragma unroll
        for (int j = 0; j < 2; ++j) acc[i][j] = (f32x4){0.f, 0.f, 0.f, 0.f};

    auto mfmaStep = [&](const unsigned short* Asb, const BP& P) {
#pragma unroll
        for (int ks = 0; ks < 2; ++ks) {
            const int cswz = (((ks * 4 + quad) ^ (lm & 7)) << 3);
            fp16x8 aF[4];
#pragma unroll
            for (int mi = 0; mi < 4; ++mi)
                aF[mi] = *(const fp16x8*)&Asb[((wm + mi * 16 + lm) << 6) + cswz];
#pragma unroll
            for (int ni = 0; ni < 2; ++ni) {
                const int u = ks * 2 + ni;
                const fp16x8 bF = decodeBF(P.b0[u], P.b1[u], P.b2[u], P.nrm[u]);
                __builtin_amdgcn_s_setprio(1);
#pragma unroll
                for (int mi = 0; mi < 4; ++mi)
                    acc[mi][ni] = __builtin_amdgcn_mfma_f32_16x16x32_f16(
                        aF[mi], bF, acc[mi][ni], 0, 0, 0);
                __builtin_amdgcn_s_setprio(0);
            }
        }
    };

    BP Pa, Pb;

    stageA(0, 0);
    loadBP(0, Pa);
    __syncthreads();

    for (int it = 0; it < NT; it += 2) {
        stageA(it + 1, 1);
        __builtin_amdgcn_sched_barrier(0);
        loadBP(it + 1, Pb);
        __builtin_amdgcn_sched_barrier(0);
        mfmaStep(As[0], Pa);
        __builtin_amdgcn_sched_barrier(0);
        if (it + 2 < NT) {
            asm volatile("s_waitcnt vmcnt(16)" ::: "memory");
        } else {
            asm volatile("s_waitcnt vmcnt(0)" ::: "memory");
        }
        __builtin_amdgcn_s_barrier();
        __builtin_amdgcn_sched_barrier(0);

        if (it + 2 < NT) stageA(it + 2, 0);
        __builtin_amdgcn_sched_barrier(0);
        if (it + 2 < NT) loadBP(it + 2, Pa);
        __builtin_amdgcn_sched_barrier(0);
        mfmaStep(As[1], Pb);
        __builtin_amdgcn_sched_barrier(0);
        if (it + 2 < NT) {
            asm volatile("s_waitcnt vmcnt(16)" ::: "memory");
        } else {
            asm volatile("s_waitcnt vmcnt(0)" ::: "memory");
        }
        __builtin_amdgcn_s_barrier();
        __builtin_amdgcn_sched_barrier(0);
    }

#pragma unroll
    for (int ni = 0; ni < 2; ++ni) {
        const int o  = n0 + wn_ + ni * 16 + lm;
        const float bv = bias[o];
#pragma unroll
        for (int mi = 0; mi < 4; ++mi) {
#pragma unroll
            for (int r = 0; r < 4; ++r) {
                const int m = m0 + wm + mi * 16 + quad * 4 + r;
                out[m * N_TOTAL + o] = acc[mi][ni][r] + bv;
            }
        }
    }
}

// ---------------- last fallback (r2 kernel) if ws tiny ----------------
__global__ void __launch_bounds__(256)
l3b_gemm_kernel(const float* __restrict__ x, const int* __restrict__ wq,
                const void* __restrict__ wnorm, const float* __restrict__ bias,
                float* __restrict__ out)
{
    __shared__ unsigned short As[128 * LDK];
    __shared__ unsigned short Bs[64 * LDK];

    const int mode = detect_mode_wave(wnorm);
    const int tid  = threadIdx.x;
    const int m0   = blockIdx.y * 128;
    const int n0   = blockIdx.x * 64;
    const int wid  = tid >> 6;
    const int lane = tid & 63;
    const int quad = lane >> 4;
    const int lm   = lane & 15;
    const int wm   = (wid >> 1) * 64;
    const int wn   = (wid & 1) * 32;

    f32x4 acc[4][2];
#pragma unroll
    for (int i = 0; i < 4; ++i)
#pragma unroll
        for (int j = 0; j < 2; ++j) acc[i][j] = (f32x4){0.f, 0.f, 0.f, 0.f};

    const int ar = tid >> 4;
    const int ac = (tid & 15) * 4;
    const int gin      = tid >> 1;
    const int half     = tid & 1;
    const int bn_local = gin >> 1;
    const int bkg      = gin & 1;

    for (int it = 0; it < NT; ++it) {
        const int k0 = it * BK;
        __syncthreads();
#pragma unroll
        for (int p = 0; p < 8; ++p) {
            const int row = p * 16 + ar;
            const float4 v = *(const float4*)&x[(m0 + row) * K_TOTAL + k0 + ac];
            *(uint2*)&As[row * LDK + ac] =
                make_uint2(pack2_bf16(v.x, v.y), pack2_bf16(v.z, v.w));
        }
        {
            const int g    = (n0 + bn_local) * (K_TOTAL / 32) + it * 2 + bkg;
            const int base = g * 12 + half * 6;
            const int2 w0 = *(const int2*)&wq[base];
            const int2 w1 = *(const int2*)&wq[base + 2];
            const int2 w2 = *(const int2*)&wq[base + 4];
            float nrm = load_norm_mode(wnorm, mode, g);
            const float a = nrm * (2.0f / 7.0f);
            const float b = -nrm;
            const unsigned int bits0 =
                (unsigned)w0.x | ((unsigned)w0.y << 8) | ((unsigned)w1.x << 16);
            const unsigned int bits1 =
                (unsigned)w1.y | ((unsigned)w2.x << 8) | ((unsigned)w2.y << 16);
            unsigned int packs[8];
#pragma unroll
            for (int t3 = 0; t3 < 2; ++t3) {
                const unsigned int bits = t3 ? bits1 : bits0;
#pragma unroll
                for (int j = 0; j < 4; ++j) {
                    const float f0 = fmaf((float)((bits >> (6 * j)) & 7), a, b);
                    const float f1 = fmaf((float)((bits >> (6 * j + 3)) & 7), a, b);
                    packs[t3 * 4 + j] = pack2_bf16(f0, f1);
                }
            }
            unsigned int* dst = (unsigned int*)&Bs[bn_local * LDK + bkg * 32 + half * 16];
            *(uint4*)dst       = make_uint4(packs[0], packs[1], packs[2], packs[3]);
            *(uint4*)(dst + 4) = make_uint4(packs[4], packs[5], packs[6], packs[7]);
        }
        __syncthreads();
#pragma unroll
        for (int ks = 0; ks < 2; ++ks) {
            const int kb = ks * 32 + quad * 8;
            bf16x8 aF[4], bF[2];
#pragma unroll
            for (int mi = 0; mi < 4; ++mi)
                aF[mi] = *(const bf16x8*)&As[(wm + mi * 16 + lm) * LDK + kb];
#pragma unroll
            for (int ni = 0; ni < 2; ++ni)
                bF[ni] = *(const bf16x8*)&Bs[(wn + ni * 16 + lm) * LDK + kb];
#pragma unroll
            for (int mi = 0; mi < 4; ++mi)
#pragma unroll
                for (int ni = 0; ni < 2; ++ni)
                    acc[mi][ni] = __builtin_amdgcn_mfma_f32_16x16x32_bf16(
                        aF[mi], bF[ni], acc[mi][ni], 0, 0, 0);
        }
    }
#pragma unroll
    for (int ni = 0; ni < 2; ++ni) {
        const int o  = n0 + wn + ni * 16 + lm;
        const float bv = bias[o];
#pragma unroll
        for (int mi = 0; mi < 4; ++mi)
#pragma unroll
            for (int r = 0; r < 4; ++r) {
                const int m = m0 + wm + mi * 16 + quad * 4 + r;
                out[m * N_TOTAL + o] = acc[mi][ni][r] + bv;
            }
    }
}

extern "C" void kernel_launch(void* const* d_in, const int* in_sizes, int n_in,
                              void* d_out, int out_size, void* d_ws, size_t ws_size,
                              hipStream_t stream) {
    const float* x    = (const float*)d_in[0];
    const int*   wq   = (const int*)d_in[1];
    const void*  wn   = d_in[2];
    const float* bias = (const float*)d_in[3];
    float* out = (float*)d_out;

    const size_t xbBytes = (size_t)M_TOTAL * K_TOTAL * 2;        // 4 MB
    const size_t wfBytes = (size_t)N_TOTAL * K_TOTAL * 2;        // 90.2 MB
    const size_t need_full = 256 + xbBytes + wfBytes;
    const size_t need_mid  = 256 + xbBytes;

    if (ws_size >= need_full) {
        unsigned short* xb = (unsigned short*)((char*)d_ws + 256);
        unsigned short* wf = (unsigned short*)((char*)d_ws + 256 + xbBytes);
        convert_x_kernel<<<(M_TOTAL * K_TOTAL / 4) / 256, 256, 0, stream>>>(x, xb);
        decode_w_kernel<<<NUM_GROUPS / 256, 256, 0, stream>>>(wq, wn, wf);
        l3b_gemm_ws<<<(M_TOTAL / BM) * (N_TOTAL / BN), 256, 0, stream>>>(
            xb, wf, bias, out);
    } else if (ws_size >= need_mid) {
        unsigned short* xb = (unsigned short*)((char*)d_ws + 256);
        convert_x_kernel<<<(M_TOTAL * K_TOTAL / 4) / 256, 256, 0, stream>>>(x, xb);
        l3b_gemm_pipe<<<(M_TOTAL / BM) * (N_TOTAL / BN), 256, 0, stream>>>(
            xb, wq, wn, bias, out);
    } else {
        dim3 grid(N_TOTAL / 64, M_TOTAL / 128);
        l3b_gemm_kernel<<<grid, 256, 0, stream>>>(x, wq, wn, bias, out);
    }
}